// Round 2
// baseline (306.374 us; speedup 1.0000x reference)
//
#include <hip/hip_runtime.h>
#include <stdint.h>

#define ALPHA_ 0.7f
constexpr int Tn = 256, Vn = 256, Qn = 32, Fn = 64, Dn = 512;
constexpr int Mn = Tn * Qn;   // 8192
constexpr int Nn = Vn * Fn;   // 16384
constexpr int Kn = Dn;        // 512

typedef float  f32x4  __attribute__((ext_vector_type(4)));
typedef __bf16 bf16x8 __attribute__((ext_vector_type(8)));

static __device__ __forceinline__ unsigned short f2bf(float f) {
  uint32_t x = __builtin_bit_cast(uint32_t, f);
  x += 0x7fffu + ((x >> 16) & 1u);   // round-to-nearest-even
  return (unsigned short)(x >> 16);
}

static __device__ __forceinline__ void gload_lds16(const void* g, void* l) {
  __builtin_amdgcn_global_load_lds(
      (const __attribute__((address_space(1))) uint32_t*)g,
      (__attribute__((address_space(3))) uint32_t*)l, 16, 0, 0);
}

// ---- kernel 1/2: L2-normalize rows of [R][512] f32 -> bf16 ----
__global__ void normalize_rows(const float* __restrict__ src,
                               uint4* __restrict__ dst) {
  const int wave = threadIdx.x >> 6;
  const int lane = threadIdx.x & 63;
  const int row  = blockIdx.x * 4 + wave;
  const float4* p = reinterpret_cast<const float4*>(src + (size_t)row * Dn + lane * 8);
  float4 x0 = p[0];
  float4 x1 = p[1];
  float ss = x0.x*x0.x + x0.y*x0.y + x0.z*x0.z + x0.w*x0.w
           + x1.x*x1.x + x1.y*x1.y + x1.z*x1.z + x1.w*x1.w;
  #pragma unroll
  for (int m = 1; m < 64; m <<= 1) ss += __shfl_xor(ss, m, 64);
  const float inv = 1.0f / fmaxf(sqrtf(ss), 1e-12f);
  union { unsigned short u[8]; uint4 v; } pk;
  const float f[8] = {x0.x, x0.y, x0.z, x0.w, x1.x, x1.y, x1.z, x1.w};
  #pragma unroll
  for (int j = 0; j < 8; ++j) pk.u[j] = f2bf(f[j] * inv);
  dst[(size_t)row * (Dn / 8) + lane] = pk.v;
}

// ---- kernel 3: out[t*V+v] = alpha*scale*dot(text[t], clip[v]) (fp32) ----
__global__ void gsim_kernel(const float* __restrict__ text,
                            const float* __restrict__ clip,
                            const float* __restrict__ logit_scale,
                            float* __restrict__ out) {
  const int idx = blockIdx.x * blockDim.x + threadIdx.x;  // t*256 + v
  const int t = idx >> 8, v = idx & 255;
  const float scale = fminf(expf(logit_scale[0]), 100.0f);
  const float4* a = reinterpret_cast<const float4*>(text + (size_t)t * Dn);
  const float4* b = reinterpret_cast<const float4*>(clip + (size_t)v * Dn);
  float s = 0.f;
  #pragma unroll 8
  for (int i = 0; i < Dn / 4; ++i) {
    float4 x = a[i], y = b[i];
    s += x.x*y.x + x.y*y.y + x.z*y.z + x.w*y.w;
  }
  out[idx] = ALPHA_ * scale * s;
}

// ---- kernel 4: fused MaxSim GEMM ----
// A = nc_bf16 [8192][512], B = nf_bf16 [16384][512]; C = A.B^T (never stored);
// per (t,v): out += (1-alpha)*scale*mean_q(max_f C).
// BM=BN=128, BK=64; 4 waves in 2x2; XOR-swizzled LDS (both-sides involution).
__global__ __launch_bounds__(256)
void maxsim_kernel(const uint16_t* __restrict__ Abf,
                   const uint16_t* __restrict__ Bbf,
                   const float* __restrict__ logit_scale,
                   float* __restrict__ out) {
  __shared__ __align__(16) unsigned char lds[32768];  // A: [0,16K), B: [16K,32K)
  const int tid  = threadIdx.x;
  const int lane = tid & 63;
  const int wave = tid >> 6;
  const int wr   = wave >> 1;   // wave row (0..1) -> 64 rows each
  const int wc   = wave & 1;    // wave col (0..1) -> 64 cols each
  const int bx   = blockIdx.x;  // 0..127 (N blocks)
  const int by   = blockIdx.y;  // 0..63  (M blocks)

  const char* Ab = reinterpret_cast<const char*>(Abf) + (size_t)by * 128 * (Kn * 2);
  const char* Bb = reinterpret_cast<const char*>(Bbf) + (size_t)bx * 128 * (Kn * 2);

  f32x4 acc[4][4];
  #pragma unroll
  for (int i = 0; i < 4; ++i)
    #pragma unroll
    for (int j = 0; j < 4; ++j)
      acc[i][j] = {0.f, 0.f, 0.f, 0.f};

  const int rA = lane & 15;
  const int kg = lane >> 4;

  for (int kt = 0; kt < Kn / 64; ++kt) {  // 8 K-tiles of 64
    // stage: linear LDS dest (wave-uniform base), inverse-swizzled global src
    #pragma unroll
    for (int i = 0; i < 4; ++i) {
      const int o   = i * 4096 + wave * 1024 + lane * 16;  // flat LDS offset
      const int row = o >> 7;                              // tile row 0..127
      const int c   = (o & 127) ^ ((row & 7) << 4);        // swizzled k-byte
      gload_lds16(Ab + (size_t)row * 1024 + kt * 128 + c,
                  &lds[i * 4096 + wave * 1024]);
      gload_lds16(Bb + (size_t)row * 1024 + kt * 128 + c,
                  &lds[16384 + i * 4096 + wave * 1024]);
    }
    __syncthreads();  // drains vmcnt

    #pragma unroll
    for (int kk = 0; kk < 2; ++kk) {
      bf16x8 af[4], bfr[4];
      #pragma unroll
      for (int mi = 0; mi < 4; ++mi) {
        const int row = wr * 64 + mi * 16 + rA;
        const int kb  = kk * 64 + kg * 16;
        af[mi] = *reinterpret_cast<const bf16x8*>(
            &lds[row * 128 + (kb ^ ((row & 7) << 4))]);
      }
      #pragma unroll
      for (int ni = 0; ni < 4; ++ni) {
        const int row = wc * 64 + ni * 16 + rA;
        const int kb  = kk * 64 + kg * 16;
        bfr[ni] = *reinterpret_cast<const bf16x8*>(
            &lds[16384 + row * 128 + (kb ^ ((row & 7) << 4))]);
      }
      #pragma unroll
      for (int mi = 0; mi < 4; ++mi)
        #pragma unroll
        for (int ni = 0; ni < 4; ++ni)
          acc[mi][ni] = __builtin_amdgcn_mfma_f32_16x16x32_bf16(
              af[mi], bfr[ni], acc[mi][ni], 0, 0, 0);
    }
    __syncthreads();
  }

  // epilogue: max over f (64 cols of this wave = one v), mean over q (32 rows)
  // C/D layout: col = lane&15, row = (lane>>4)*4 + reg   [m89-verified]
  const float scale = fminf(expf(logit_scale[0]), 100.0f);
  const float coef  = (1.0f - ALPHA_) * scale / (float)Qn;

  float sums[2] = {0.f, 0.f};
  #pragma unroll
  for (int mi = 0; mi < 4; ++mi) {
    #pragma unroll
    for (int reg = 0; reg < 4; ++reg) {
      float rm = fmaxf(fmaxf(acc[mi][0][reg], acc[mi][1][reg]),
                       fmaxf(acc[mi][2][reg], acc[mi][3][reg]));
      rm = fmaxf(rm, __shfl_xor(rm, 1, 64));
      rm = fmaxf(rm, __shfl_xor(rm, 2, 64));
      rm = fmaxf(rm, __shfl_xor(rm, 4, 64));
      rm = fmaxf(rm, __shfl_xor(rm, 8, 64));  // row-max over all 64 cols
      sums[mi >> 1] += rm;                    // mi 0,1 -> t-group 0; 2,3 -> 1
    }
  }
  #pragma unroll
  for (int s = 0; s < 2; ++s) {
    float v = sums[s];
    v += __shfl_xor(v, 16, 64);
    v += __shfl_xor(v, 32, 64);  // sum over the 4 hi-groups -> 32 rows
    sums[s] = v;
  }
  if (lane == 0) {
    const int v = bx * 2 + wc;
    #pragma unroll
    for (int s = 0; s < 2; ++s) {
      const int t = by * 4 + wr * 2 + s;
      const int idx = t * Vn + v;
      out[idx] = out[idx] + coef * sums[s];  // g_sim already written
    }
  }
}

extern "C" void kernel_launch(void* const* d_in, const int* in_sizes, int n_in,
                              void* d_out, int out_size, void* d_ws, size_t ws_size,
                              hipStream_t stream) {
  const float* text        = (const float*)d_in[0];
  const float* clip        = (const float*)d_in[1];
  const float* concept     = (const float*)d_in[2];
  const float* frames      = (const float*)d_in[3];
  const float* logit_scale = (const float*)d_in[4];
  float* out = (float*)d_out;

  uint16_t* Abf = (uint16_t*)d_ws;              //  8192*512 bf16 = 8 MiB
  uint16_t* Bbf = Abf + (size_t)Mn * Kn;        // 16384*512 bf16 = 16 MiB

  normalize_rows<<<Mn / 4, 256, 0, stream>>>(concept, (uint4*)Abf);
  normalize_rows<<<Nn / 4, 256, 0, stream>>>(frames, (uint4*)Bbf);
  gsim_kernel<<<Tn, 256, 0, stream>>>(text, clip, logit_scale, out);
  dim3 grid(Nn / 128, Mn / 128);
  maxsim_kernel<<<grid, 256, 0, stream>>>(Abf, Bbf, logit_scale, out);
}

// Round 3
// 231.084 us; speedup vs baseline: 1.3258x; 1.3258x over previous
//
#include <hip/hip_runtime.h>
#include <stdint.h>

#define ALPHA_ 0.7f
constexpr int Tn = 256, Vn = 256, Qn = 32, Fn = 64, Dn = 512;
constexpr int Mn = Tn * Qn;   // 8192
constexpr int Nn = Vn * Fn;   // 16384
constexpr int Kn = Dn;        // 512
constexpr int NT = Kn / 64;   // 8 K-tiles

typedef float  f32x4  __attribute__((ext_vector_type(4)));
typedef __bf16 bf16x8 __attribute__((ext_vector_type(8)));

static __device__ __forceinline__ unsigned short f2bf(float f) {
  uint32_t x = __builtin_bit_cast(uint32_t, f);
  x += 0x7fffu + ((x >> 16) & 1u);   // round-to-nearest-even
  return (unsigned short)(x >> 16);
}

static __device__ __forceinline__ void gload_lds16(const void* g, void* l) {
  __builtin_amdgcn_global_load_lds(
      (const __attribute__((address_space(1))) uint32_t*)g,
      (__attribute__((address_space(3))) uint32_t*)l, 16, 0, 0);
}

#define BAR()   asm volatile("s_barrier" ::: "memory")
#define LGKM0() do { asm volatile("s_waitcnt lgkmcnt(0)" ::: "memory"); \
                     __builtin_amdgcn_sched_barrier(0); } while (0)
#define VM6()   asm volatile("s_waitcnt vmcnt(6)" ::: "memory")
#define VM0()   asm volatile("s_waitcnt vmcnt(0)" ::: "memory")

// ---- kernel 1/2: L2-normalize rows of [R][512] f32 -> bf16 ----
__global__ void normalize_rows(const float* __restrict__ src,
                               uint4* __restrict__ dst) {
  const int wave = threadIdx.x >> 6;
  const int lane = threadIdx.x & 63;
  const int row  = blockIdx.x * 4 + wave;
  const float4* p = reinterpret_cast<const float4*>(src + (size_t)row * Dn + lane * 8);
  float4 x0 = p[0];
  float4 x1 = p[1];
  float ss = x0.x*x0.x + x0.y*x0.y + x0.z*x0.z + x0.w*x0.w
           + x1.x*x1.x + x1.y*x1.y + x1.z*x1.z + x1.w*x1.w;
  #pragma unroll
  for (int m = 1; m < 64; m <<= 1) ss += __shfl_xor(ss, m, 64);
  const float inv = 1.0f / fmaxf(sqrtf(ss), 1e-12f);
  union { unsigned short u[8]; uint4 v; } pk;
  const float f[8] = {x0.x, x0.y, x0.z, x0.w, x1.x, x1.y, x1.z, x1.w};
  #pragma unroll
  for (int j = 0; j < 8; ++j) pk.u[j] = f2bf(f[j] * inv);
  dst[(size_t)row * (Dn / 8) + lane] = pk.v;
}

// ---- fused MaxSim GEMM, 256x256 tile, 8-phase schedule (m201 template) ----
// A = nc_bf16 [8192][512], B = nf_bf16 [16384][512]; C = A.B^T never stored.
// 8 waves (2M x 4N): per-wave C = 128 rows x 64 cols = 8x4 frags of 16x16.
// K-tile = 64. LDS: 2 dbuf x (A: 2 halves + B: 2 halves) x 16KB = 128 KiB.
// A-half h = rows {64h..64h+63} u {128+64h..128+64h+63} (matches quadrant reads).
// B-half h = cols {32h..} u {64+32h..} u {128+32h..} u {192+32h..}.
// Phases/tile: q=(0,0) [ldA0,ldB0 12 reads] -> (0,1) [ldB1 4] -> (1,1) [ldA1 8]
// -> (1,0) [0 reads]. Stages: p1: A1'(t+1); p2: A0'(t+2); p3: B0'(t+2);
// p4: B1'(t+2). vmcnt(6) at tile boundary (3 halves = 6 loads in flight);
// vmcnt(0) only entering the last tile. Epilogue fuses g_sim (f32 dots).
__global__ __launch_bounds__(512, 2)
void maxsim256_kernel(const uint16_t* __restrict__ Abf,
                      const uint16_t* __restrict__ Bbf,
                      const float* __restrict__ text,
                      const float* __restrict__ clip,
                      const float* __restrict__ logit_scale,
                      float* __restrict__ out) {
  __shared__ __align__(16) unsigned char lds[131072];
  const int tid  = threadIdx.x;
  const int lane = tid & 63;
  const int wave = tid >> 6;    // 0..7
  const int wr   = wave >> 2;   // 0..1 -> rows [wr*128, +128)
  const int wc   = wave & 3;    // 0..3 -> cols [wc*64, +64)
  const int bx   = blockIdx.x;  // 0..63  (N)
  const int by   = blockIdx.y;  // 0..31  (M)

  const char* Ag = reinterpret_cast<const char*>(Abf) + (size_t)by * 256 * 1024;
  const char* Bg = reinterpret_cast<const char*>(Bbf) + (size_t)bx * 256 * 1024;

  // stage one half (16KB): 2 x gload_lds16 per thread; linear LDS dest,
  // inverse-permuted global source (row perm + (r&7)<<4 XOR swizzle).
  auto stage = [&](int buf, int isB, int h, int tile) {
    const char* g = isB ? Bg : Ag;
    const unsigned base = buf * 65536 + isB * 32768 + h * 16384;
    #pragma unroll
    for (int j = 0; j < 2; ++j) {
      const unsigned flat = (j * 8 + wave) * 1024 + lane * 16;
      const unsigned r = flat >> 7, c0 = flat & 127;
      const unsigned R = isB ? ((r >> 5) << 6) + h * 32 + (r & 31)
                             : ((r >> 6) << 7) + h * 64 + (r & 63);
      gload_lds16(g + (size_t)R * 1024 + tile * 128 + (c0 ^ ((r & 7) << 4)),
                  &lds[base + (j * 8 + wave) * 1024]);
    }
  };

  f32x4 acc[8][4];
  #pragma unroll
  for (int i = 0; i < 8; ++i)
    #pragma unroll
    for (int j = 0; j < 4; ++j)
      acc[i][j] = {0.f, 0.f, 0.f, 0.f};

  bf16x8 af[4][2];   // current A-quadrant frags (mi = hm*4+m)
  bf16x8 bq[4][2];   // all B frags of current tile (ni, kk)

  const int rA  = lane & 15;
  const int kg  = lane >> 4;
  const unsigned key = (unsigned)(rA & 7) << 4;

  auto ldA = [&](int buf, int h) {
    const unsigned b = buf * 65536 + h * 16384;
    #pragma unroll
    for (int m = 0; m < 4; ++m) {
      const unsigned s = (unsigned)(wr * 64 + m * 16 + rA);
      #pragma unroll
      for (int kk = 0; kk < 2; ++kk) {
        const unsigned kb = kk * 64 + kg * 16;
        af[m][kk] = *reinterpret_cast<const bf16x8*>(&lds[b + s * 128 + (kb ^ key)]);
      }
    }
  };
  auto ldB = [&](int buf, int h) {
    const unsigned b = buf * 65536 + 32768 + h * 16384;
    #pragma unroll
    for (int n = 0; n < 2; ++n) {
      const unsigned s = (unsigned)(wc * 32 + n * 16 + rA);
      #pragma unroll
      for (int kk = 0; kk < 2; ++kk) {
        const unsigned kb = kk * 64 + kg * 16;
        bq[h * 2 + n][kk] = *reinterpret_cast<const bf16x8*>(&lds[b + s * 128 + (kb ^ key)]);
      }
    }
  };
  auto mfma_quad = [&](int hm, int hn) {
    __builtin_amdgcn_s_setprio(1);
    #pragma unroll
    for (int m = 0; m < 4; ++m)
      #pragma unroll
      for (int n = 0; n < 2; ++n)
        #pragma unroll
        for (int kk = 0; kk < 2; ++kk) {
          const int mi = hm * 4 + m, ni = hn * 2 + n;
          acc[mi][ni] = __builtin_amdgcn_mfma_f32_16x16x32_bf16(
              af[m][kk], bq[ni][kk], acc[mi][ni], 0, 0, 0);
        }
    __builtin_amdgcn_s_setprio(0);
  };

  // prologue: tile0 fully, tile1 {A0',B0',B1'} -> vmcnt(6) = tile0 landed
  stage(0, 0, 0, 0); stage(0, 1, 0, 0); stage(0, 1, 1, 0); stage(0, 0, 1, 0);
  stage(1, 0, 0, 1); stage(1, 1, 0, 1); stage(1, 1, 1, 1);
  VM6(); BAR();

  auto tile_step = [&](int t, int buf) {
    // P1: quadrant (0,0)
    ldA(buf, 0); ldB(buf, 0);
    if (t + 1 < NT) stage(buf ^ 1, 0, 1, t + 1);          // A1'(t+1)
    asm volatile("s_waitcnt lgkmcnt(8)" ::: "memory");
    BAR(); LGKM0();
    mfma_quad(0, 0);
    BAR();
    // P2: quadrant (0,1)
    ldB(buf, 1);
    if (t + 2 < NT) stage(buf, 0, 0, t + 2);              // A0'(t+2)
    BAR(); LGKM0();
    mfma_quad(0, 1);
    BAR();
    // P3: quadrant (1,1)
    ldA(buf, 1);
    if (t + 2 < NT) stage(buf, 1, 0, t + 2);              // B0'(t+2)
    BAR(); LGKM0();
    mfma_quad(1, 1);
    BAR();
    // P4: quadrant (1,0) — all frags already in registers
    if (t + 2 < NT) stage(buf, 1, 1, t + 2);              // B1'(t+2)
    BAR();
    mfma_quad(1, 0);
    if (t < NT - 2) { VM6(); } else { VM0(); }
    BAR();
  };

  for (int t = 0; t < NT; t += 2) {
    tile_step(t, 0);
    tile_step(t + 1, 1);
  }

  // ---- epilogue: per wave 4 outputs (t = by*8+wr*4+g, v = bx*4+wc) ----
  // C/D layout: col = lane&15, row = (lane>>4)*4 + reg  [m89-verified]
  const float scale = fminf(expf(logit_scale[0]), 100.0f);
  const int v_out = bx * 4 + wc;
  const float4* cp = reinterpret_cast<const float4*>(clip + (size_t)v_out * Dn) + lane * 2;
  const float4 c0 = cp[0], c1 = cp[1];

  #pragma unroll
  for (int g = 0; g < 4; ++g) {
    float sum = 0.f;
    #pragma unroll
    for (int m2 = 0; m2 < 2; ++m2) {
      const int mi = g * 2 + m2;
      #pragma unroll
      for (int reg = 0; reg < 4; ++reg) {
        float rm = fmaxf(fmaxf(acc[mi][0][reg], acc[mi][1][reg]),
                         fmaxf(acc[mi][2][reg], acc[mi][3][reg]));
        rm = fmaxf(rm, __shfl_xor(rm, 1, 64));
        rm = fmaxf(rm, __shfl_xor(rm, 2, 64));
        rm = fmaxf(rm, __shfl_xor(rm, 4, 64));
        rm = fmaxf(rm, __shfl_xor(rm, 8, 64));   // max over all 64 f-cols
        sum += rm;
      }
    }
    sum += __shfl_xor(sum, 16, 64);
    sum += __shfl_xor(sum, 32, 64);              // sum over 32 q-rows

    const int t_out = by * 8 + wr * 4 + g;
    const float4* tp = reinterpret_cast<const float4*>(text + (size_t)t_out * Dn) + lane * 2;
    const float4 t0 = tp[0], t1 = tp[1];
    float gd = t0.x*c0.x + t0.y*c0.y + t0.z*c0.z + t0.w*c0.w
             + t1.x*c1.x + t1.y*c1.y + t1.z*c1.z + t1.w*c1.w;
    gd += __shfl_xor(gd, 1, 64);  gd += __shfl_xor(gd, 2, 64);
    gd += __shfl_xor(gd, 4, 64);  gd += __shfl_xor(gd, 8, 64);
    gd += __shfl_xor(gd, 16, 64); gd += __shfl_xor(gd, 32, 64);

    if (lane == 0)
      out[t_out * Vn + v_out] =
          ALPHA_ * scale * gd + (1.0f - ALPHA_) * scale * (sum * (1.0f / (float)Qn));
  }
}

extern "C" void kernel_launch(void* const* d_in, const int* in_sizes, int n_in,
                              void* d_out, int out_size, void* d_ws, size_t ws_size,
                              hipStream_t stream) {
  const float* text        = (const float*)d_in[0];
  const float* clip        = (const float*)d_in[1];
  const float* concept     = (const float*)d_in[2];
  const float* frames      = (const float*)d_in[3];
  const float* logit_scale = (const float*)d_in[4];
  float* out = (float*)d_out;

  uint16_t* Abf = (uint16_t*)d_ws;              //  8192*512 bf16 = 8 MiB
  uint16_t* Bbf = Abf + (size_t)Mn * Kn;        // 16384*512 bf16 = 16 MiB

  normalize_rows<<<Mn / 4, 256, 0, stream>>>(concept, (uint4*)Abf);
  normalize_rows<<<Nn / 4, 256, 0, stream>>>(frames, (uint4*)Bbf);
  dim3 grid(Nn / 256, Mn / 256);
  maxsim256_kernel<<<grid, 512, 0, stream>>>(Abf, Bbf, text, clip, logit_scale, out);
}

// Round 4
// 228.629 us; speedup vs baseline: 1.3400x; 1.0107x over previous
//
#include <hip/hip_runtime.h>
#include <stdint.h>

#define ALPHA_ 0.7f
constexpr int Tn = 256, Vn = 256, Qn = 32, Fn = 64, Dn = 512;
constexpr int Mn = Tn * Qn;   // 8192
constexpr int Nn = Vn * Fn;   // 16384
constexpr int Kn = Dn;        // 512
constexpr int NOT = 8;        // N-otiles per block
constexpr int GT  = (Kn / 64) * NOT;  // 64 flat K-steps per block

typedef float  f32x4  __attribute__((ext_vector_type(4)));
typedef __bf16 bf16x8 __attribute__((ext_vector_type(8)));

static __device__ __forceinline__ unsigned short f2bf(float f) {
  uint32_t x = __builtin_bit_cast(uint32_t, f);
  x += 0x7fffu + ((x >> 16) & 1u);   // round-to-nearest-even
  return (unsigned short)(x >> 16);
}

static __device__ __forceinline__ void gload_lds16(const void* g, void* l) {
  __builtin_amdgcn_global_load_lds(
      (const __attribute__((address_space(1))) uint32_t*)g,
      (__attribute__((address_space(3))) uint32_t*)l, 16, 0, 0);
}

#define BAR()   asm volatile("s_barrier" ::: "memory")
#define LGKM0() do { asm volatile("s_waitcnt lgkmcnt(0)" ::: "memory"); \
                     __builtin_amdgcn_sched_barrier(0); } while (0)
#define VM6()   asm volatile("s_waitcnt vmcnt(6)" ::: "memory")
#define VM0()   asm volatile("s_waitcnt vmcnt(0)" ::: "memory")

// ---- kernel 1/2: L2-normalize rows of [R][512] f32 -> bf16 ----
__global__ void normalize_rows(const float* __restrict__ src,
                               uint4* __restrict__ dst) {
  const int wave = threadIdx.x >> 6;
  const int lane = threadIdx.x & 63;
  const int row  = blockIdx.x * 4 + wave;
  const float4* p = reinterpret_cast<const float4*>(src + (size_t)row * Dn + lane * 8);
  float4 x0 = p[0];
  float4 x1 = p[1];
  float ss = x0.x*x0.x + x0.y*x0.y + x0.z*x0.z + x0.w*x0.w
           + x1.x*x1.x + x1.y*x1.y + x1.z*x1.z + x1.w*x1.w;
  #pragma unroll
  for (int m = 1; m < 64; m <<= 1) ss += __shfl_xor(ss, m, 64);
  const float inv = 1.0f / fmaxf(sqrtf(ss), 1e-12f);
  union { unsigned short u[8]; uint4 v; } pk;
  const float f[8] = {x0.x, x0.y, x0.z, x0.w, x1.x, x1.y, x1.z, x1.w};
  #pragma unroll
  for (int j = 0; j < 8; ++j) pk.u[j] = f2bf(f[j] * inv);
  dst[(size_t)row * (Dn / 8) + lane] = pk.v;
}

// ---- fused MaxSim GEMM, persistent 256x256 tiles, 8-phase schedule ----
// 256 blocks, 1/CU. Block (by = bid>>3, nx0 = (bid&7)*8) sweeps 8 N-tiles
// with its fixed M-panel; flat K-step g = otile*8 + ktile, 64 steps, the
// prefetch pipeline (stage g+1 A1; g+2 A0,B0,B1; vmcnt(6)) never drains.
// The bid&7 grouping puts all blocks of one N-chunk on one XCD (%8 mapping):
// the 2MB B-chunk is L2-resident. Per-otile epilogue in the VM6 shadow.
__global__ __launch_bounds__(512, 2)
void maxsim256_kernel(const uint16_t* __restrict__ Abf,
                      const uint16_t* __restrict__ Bbf,
                      const float* __restrict__ text,
                      const float* __restrict__ clip,
                      const float* __restrict__ logit_scale,
                      float* __restrict__ out) {
  __shared__ __align__(16) unsigned char lds[131072];
  const int tid  = threadIdx.x;
  const int lane = tid & 63;
  const int wave = tid >> 6;    // 0..7
  const int wr   = wave >> 2;   // 0..1 -> rows [wr*128, +128)
  const int wc   = wave & 3;    // 0..3 -> cols [wc*64, +64)
  const int bid  = blockIdx.x;  // 0..255
  const int nx0  = (bid & 7) * 8;   // first N-tile of this block's chunk
  const int by   = bid >> 3;        // M-tile 0..31

  const float scale = fminf(expf(logit_scale[0]), 100.0f);
  const float coefG = ALPHA_ * scale;
  const float coefL = (1.0f - ALPHA_) * scale * (1.0f / (float)Qn);

  const char* Ag  = reinterpret_cast<const char*>(Abf) + (size_t)by  * 262144;
  const char* Bg0 = reinterpret_cast<const char*>(Bbf) + (size_t)nx0 * 262144;

  // per-thread staging source offsets (precomputed; j = 0,1)
  // flat = (j*8+wave)*1024 + lane*16; r = flat>>7; swz c = (flat&127)^((r&7)<<4)
  unsigned srcA[2], srcB[2], ldsoff[2];
  #pragma unroll
  for (int j = 0; j < 2; ++j) {
    const unsigned r = (j * 8 + wave) * 8 + (lane >> 3);
    const unsigned c = (((lane & 7) ^ (lane >> 3)) << 4);
    srcA[j]  = (((r >> 6) << 7) + (r & 63)) * 1024 + c;  // + h*65536 + kt*128
    srcB[j]  = (((r >> 5) << 6) + (r & 31)) * 1024 + c;  // + h*32768 + kt*128
    ldsoff[j] = (j * 8 + wave) * 1024;
  }

  // stage one 16KB half of tile g into buf: linear LDS dest, swizzled source
  auto stage = [&](int buf, int isB, int h, int g) {
    const unsigned base = buf * 65536 + isB * 32768 + h * 16384;
    const unsigned kt = (g & 7) * 128;
    #pragma unroll
    for (int j = 0; j < 2; ++j) {
      const void* src = isB
          ? (const void*)(Bg0 + (size_t)((g >> 3) * 262144 + h * 32768 + kt + srcB[j]))
          : (const void*)(Ag  + (size_t)(h * 65536 + kt + srcA[j]));
      gload_lds16(src, &lds[base + ldsoff[j]]);
    }
  };

  f32x4 acc[8][4];
  #pragma unroll
  for (int i = 0; i < 8; ++i)
    #pragma unroll
    for (int j = 0; j < 4; ++j)
      acc[i][j] = {0.f, 0.f, 0.f, 0.f};

  bf16x8 af[4][2];   // current A-quadrant frags
  bf16x8 bq[4][2];   // current tile's B frags (ni = h*2+n, kk)

  const int rA  = lane & 15;
  const int kg  = lane >> 4;
  const unsigned key = (unsigned)(rA & 7) << 4;

  auto ldA = [&](int buf, int h) {
    const unsigned b = buf * 65536 + h * 16384;
    #pragma unroll
    for (int m = 0; m < 4; ++m) {
      const unsigned s = (unsigned)(wr * 64 + m * 16 + rA);
      #pragma unroll
      for (int kk = 0; kk < 2; ++kk) {
        const unsigned kb = kk * 64 + kg * 16;
        af[m][kk] = *reinterpret_cast<const bf16x8*>(&lds[b + s * 128 + (kb ^ key)]);
      }
    }
  };
  auto ldB = [&](int buf, int h) {
    const unsigned b = buf * 65536 + 32768 + h * 16384;
    #pragma unroll
    for (int n = 0; n < 2; ++n) {
      const unsigned s = (unsigned)(wc * 32 + n * 16 + rA);
      #pragma unroll
      for (int kk = 0; kk < 2; ++kk) {
        const unsigned kb = kk * 64 + kg * 16;
        bq[h * 2 + n][kk] = *reinterpret_cast<const bf16x8*>(&lds[b + s * 128 + (kb ^ key)]);
      }
    }
  };
  auto mfma_quad = [&](int hm, int hn) {
    __builtin_amdgcn_s_setprio(1);
    #pragma unroll
    for (int m = 0; m < 4; ++m)
      #pragma unroll
      for (int n = 0; n < 2; ++n)
        #pragma unroll
        for (int kk = 0; kk < 2; ++kk) {
          const int mi = hm * 4 + m, ni = hn * 2 + n;
          acc[mi][ni] = __builtin_amdgcn_mfma_f32_16x16x32_bf16(
              af[m][kk], bq[ni][kk], acc[mi][ni], 0, 0, 0);
        }
    __builtin_amdgcn_s_setprio(0);
  };

  // per-otile epilogue: max over f (64 cols/wave), mean over q, + fused g_sim.
  // C/D layout: col = lane&15, row = (lane>>4)*4 + reg  [m89-verified]
  auto epilogue = [&](int ot) {
    const int v_out = (nx0 + ot) * 4 + wc;
    const float4* cp = reinterpret_cast<const float4*>(clip + (size_t)v_out * Dn) + lane * 2;
    const float4 c0 = cp[0], c1 = cp[1];
    float4 t0[4], t1[4];
    #pragma unroll
    for (int gq = 0; gq < 4; ++gq) {
      const float4* tp = reinterpret_cast<const float4*>(
          text + (size_t)(by * 8 + wr * 4 + gq) * Dn) + lane * 2;
      t0[gq] = tp[0]; t1[gq] = tp[1];
    }
    #pragma unroll
    for (int gq = 0; gq < 4; ++gq) {
      float sum = 0.f;
      #pragma unroll
      for (int m2 = 0; m2 < 2; ++m2) {
        const int mi = gq * 2 + m2;
        #pragma unroll
        for (int reg = 0; reg < 4; ++reg) {
          float rm = fmaxf(fmaxf(acc[mi][0][reg], acc[mi][1][reg]),
                           fmaxf(acc[mi][2][reg], acc[mi][3][reg]));
          rm = fmaxf(rm, __shfl_xor(rm, 1, 64));
          rm = fmaxf(rm, __shfl_xor(rm, 2, 64));
          rm = fmaxf(rm, __shfl_xor(rm, 4, 64));
          rm = fmaxf(rm, __shfl_xor(rm, 8, 64));   // max over all 64 f-cols
          sum += rm;
        }
      }
      sum += __shfl_xor(sum, 16, 64);
      sum += __shfl_xor(sum, 32, 64);              // sum over 32 q-rows
      float gd = t0[gq].x*c0.x + t0[gq].y*c0.y + t0[gq].z*c0.z + t0[gq].w*c0.w
               + t1[gq].x*c1.x + t1[gq].y*c1.y + t1[gq].z*c1.z + t1[gq].w*c1.w;
      gd += __shfl_xor(gd, 1, 64);  gd += __shfl_xor(gd, 2, 64);
      gd += __shfl_xor(gd, 4, 64);  gd += __shfl_xor(gd, 8, 64);
      gd += __shfl_xor(gd, 16, 64); gd += __shfl_xor(gd, 32, 64);
      if (lane == 0)
        out[(by * 8 + wr * 4 + gq) * Vn + v_out] = coefG * gd + coefL * sum;
    }
    #pragma unroll
    for (int i = 0; i < 8; ++i)
      #pragma unroll
      for (int j = 0; j < 4; ++j)
        acc[i][j] = {0.f, 0.f, 0.f, 0.f};
  };

  // prologue: tile0 fully, tile1 {A0,B0,B1} -> vmcnt(6) = tile0 landed
  stage(0, 0, 0, 0); stage(0, 1, 0, 0); stage(0, 1, 1, 0); stage(0, 0, 1, 0);
  stage(1, 0, 0, 1); stage(1, 1, 0, 1); stage(1, 1, 1, 1);
  VM6(); BAR();

  auto tile_step = [&](int g, int buf) {
    // P1: quadrant (0,0)
    ldA(buf, 0); ldB(buf, 0);
    if (g + 1 < GT) stage(buf ^ 1, 0, 1, g + 1);          // A1(g+1)
    asm volatile("s_waitcnt lgkmcnt(8)" ::: "memory");
    BAR(); LGKM0();
    mfma_quad(0, 0);
    BAR();
    // P2: quadrant (0,1)
    ldB(buf, 1);
    if (g + 2 < GT) stage(buf, 0, 0, g + 2);              // A0(g+2)
    BAR(); LGKM0();
    mfma_quad(0, 1);
    BAR();
    // P3: quadrant (1,1)
    ldA(buf, 1);
    if (g + 2 < GT) stage(buf, 1, 0, g + 2);              // B0(g+2)
    BAR(); LGKM0();
    mfma_quad(1, 1);
    BAR();
    // P4: quadrant (1,0) — all frags already in registers
    if (g + 2 < GT) stage(buf, 1, 1, g + 2);              // B1(g+2)
    BAR();
    mfma_quad(1, 0);
    if (g < GT - 2) { VM6(); } else { VM0(); }
    if ((g & 7) == 7) epilogue(g >> 3);   // otile done: reduce in VM6 shadow
    BAR();
  };

  for (int t = 0; t < GT; t += 2) {
    tile_step(t, 0);
    tile_step(t + 1, 1);
  }
}

extern "C" void kernel_launch(void* const* d_in, const int* in_sizes, int n_in,
                              void* d_out, int out_size, void* d_ws, size_t ws_size,
                              hipStream_t stream) {
  const float* text        = (const float*)d_in[0];
  const float* clip        = (const float*)d_in[1];
  const float* concept     = (const float*)d_in[2];
  const float* frames      = (const float*)d_in[3];
  const float* logit_scale = (const float*)d_in[4];
  float* out = (float*)d_out;

  uint16_t* Abf = (uint16_t*)d_ws;              //  8192*512 bf16 = 8 MiB
  uint16_t* Bbf = Abf + (size_t)Mn * Kn;        // 16384*512 bf16 = 16 MiB

  normalize_rows<<<Mn / 4, 256, 0, stream>>>(concept, (uint4*)Abf);
  normalize_rows<<<Nn / 4, 256, 0, stream>>>(frames, (uint4*)Bbf);
  maxsim256_kernel<<<256, 512, 0, stream>>>(Abf, Bbf, text, clip, logit_scale, out);
}

// Round 5
// 221.190 us; speedup vs baseline: 1.3851x; 1.0336x over previous
//
#include <hip/hip_runtime.h>
#include <stdint.h>

#define ALPHA_ 0.7f
constexpr int Tn = 256, Vn = 256, Qn = 32, Fn = 64, Dn = 512;
constexpr int Mn = Tn * Qn;   // 8192
constexpr int Nn = Vn * Fn;   // 16384
constexpr int Kn = Dn;        // 512
constexpr int NOT = 8;        // N-otiles per block
constexpr int GT  = (Kn / 64) * NOT;  // 64 flat K-steps per block

typedef float  f32x4  __attribute__((ext_vector_type(4)));
typedef __bf16 bf16x8 __attribute__((ext_vector_type(8)));

static __device__ __forceinline__ unsigned short f2bf(float f) {
  uint32_t x = __builtin_bit_cast(uint32_t, f);
  x += 0x7fffu + ((x >> 16) & 1u);   // round-to-nearest-even
  return (unsigned short)(x >> 16);
}

static __device__ __forceinline__ void gload_lds16(const void* g, void* l) {
  __builtin_amdgcn_global_load_lds(
      (const __attribute__((address_space(1))) uint32_t*)g,
      (__attribute__((address_space(3))) uint32_t*)l, 16, 0, 0);
}

#define BAR()   asm volatile("s_barrier" ::: "memory")
#define SBAR()  __builtin_amdgcn_sched_barrier(0)
#define LGKM(N) do { asm volatile("s_waitcnt lgkmcnt(" #N ")" ::: "memory"); \
                     SBAR(); } while (0)
#define VM6()   asm volatile("s_waitcnt vmcnt(6)" ::: "memory")
#define VM0()   asm volatile("s_waitcnt vmcnt(0)" ::: "memory")

// ---- kernel 1/2: L2-normalize rows of [R][512] f32 -> bf16 ----
__global__ void normalize_rows(const float* __restrict__ src,
                               uint4* __restrict__ dst) {
  const int wave = threadIdx.x >> 6;
  const int lane = threadIdx.x & 63;
  const int row  = blockIdx.x * 4 + wave;
  const float4* p = reinterpret_cast<const float4*>(src + (size_t)row * Dn + lane * 8);
  float4 x0 = p[0];
  float4 x1 = p[1];
  float ss = x0.x*x0.x + x0.y*x0.y + x0.z*x0.z + x0.w*x0.w
           + x1.x*x1.x + x1.y*x1.y + x1.z*x1.z + x1.w*x1.w;
  #pragma unroll
  for (int m = 1; m < 64; m <<= 1) ss += __shfl_xor(ss, m, 64);
  const float inv = 1.0f / fmaxf(sqrtf(ss), 1e-12f);
  union { unsigned short u[8]; uint4 v; } pk;
  const float f[8] = {x0.x, x0.y, x0.z, x0.w, x1.x, x1.y, x1.z, x1.w};
  #pragma unroll
  for (int j = 0; j < 8; ++j) pk.u[j] = f2bf(f[j] * inv);
  dst[(size_t)row * (Dn / 8) + lane] = pk.v;
}

// ---- fused MaxSim GEMM, persistent 256x256 tiles, 2-barrier/tile schedule ----
// 256 blocks, 1/CU. Block (by=bid>>3, nx0=(bid&7)*8) sweeps 8 N-tiles.
// Per tile: {rd A0,B0,B1 (16xb128, order pinned); stage A1(g+1); lgkm(4);
// MFMA q00; lgkm(0); MFMA q01; BAR; rd A1 (af reuse); stage A0,B0,B1(g+2);
// lgkm(0); MFMA q11,q10; VM6; BAR}. Counted lgkm overlaps B1 reads with q00;
// 2 barriers/tile vs 8. VM6 invariant: at each tile end the next tile's 4
// halves have landed (VM0 for the last two tiles).
__global__ __launch_bounds__(512, 2)
void maxsim256_kernel(const uint16_t* __restrict__ Abf,
                      const uint16_t* __restrict__ Bbf,
                      const float* __restrict__ text,
                      const float* __restrict__ clip,
                      const float* __restrict__ logit_scale,
                      float* __restrict__ out) {
  __shared__ __align__(16) unsigned char lds[131072];
  const int tid  = threadIdx.x;
  const int lane = tid & 63;
  const int wave = tid >> 6;    // 0..7
  const int wr   = wave >> 2;   // 0..1 -> rows [wr*128, +128)
  const int wc   = wave & 3;    // 0..3 -> cols [wc*64, +64)
  const int bid  = blockIdx.x;  // 0..255
  const int nx0  = (bid & 7) * 8;   // first N-tile of this block's chunk
  const int by   = bid >> 3;        // M-tile 0..31

  const float scale = fminf(expf(logit_scale[0]), 100.0f);
  const float coefG = ALPHA_ * scale;
  const float coefL = (1.0f - ALPHA_) * scale * (1.0f / (float)Qn);

  const char* Ag  = reinterpret_cast<const char*>(Abf) + (size_t)by  * 262144;
  const char* Bg0 = reinterpret_cast<const char*>(Bbf) + (size_t)nx0 * 262144;

  // per-thread staging source offsets (j = 0,1)
  unsigned srcA[2], srcB[2], ldsoff[2];
  #pragma unroll
  for (int j = 0; j < 2; ++j) {
    const unsigned r = (j * 8 + wave) * 8 + (lane >> 3);
    const unsigned c = (((lane & 7) ^ (lane >> 3)) << 4);
    srcA[j]  = (((r >> 6) << 7) + (r & 63)) * 1024 + c;  // + h*65536 + kt*128
    srcB[j]  = (((r >> 5) << 6) + (r & 31)) * 1024 + c;  // + h*32768 + kt*128
    ldsoff[j] = (j * 8 + wave) * 1024;
  }

  auto stage = [&](int buf, int isB, int h, int g) {
    const unsigned base = buf * 65536 + isB * 32768 + h * 16384;
    const unsigned kt = (g & 7) * 128;
    #pragma unroll
    for (int j = 0; j < 2; ++j) {
      const void* src = isB
          ? (const void*)(Bg0 + (size_t)((g >> 3) * 262144 + h * 32768 + kt + srcB[j]))
          : (const void*)(Ag  + (size_t)(h * 65536 + kt + srcA[j]));
      gload_lds16(src, &lds[base + ldsoff[j]]);
    }
  };

  f32x4 acc[8][4];
  #pragma unroll
  for (int i = 0; i < 8; ++i)
    #pragma unroll
    for (int j = 0; j < 4; ++j)
      acc[i][j] = {0.f, 0.f, 0.f, 0.f};

  bf16x8 af[4][2];   // current A-half frags (reused for A0 then A1)
  bf16x8 bq[4][2];   // whole tile's B frags (ni = h*2+n, kk)

  const int rA  = lane & 15;
  const int kg  = lane >> 4;
  const unsigned key = (unsigned)(rA & 7) << 4;

  auto ldA = [&](int buf, int h) {
    const unsigned b = buf * 65536 + h * 16384;
    #pragma unroll
    for (int m = 0; m < 4; ++m) {
      const unsigned s = (unsigned)(wr * 64 + m * 16 + rA);
      #pragma unroll
      for (int kk = 0; kk < 2; ++kk) {
        const unsigned kb = kk * 64 + kg * 16;
        af[m][kk] = *reinterpret_cast<const bf16x8*>(&lds[b + s * 128 + (kb ^ key)]);
      }
    }
  };
  auto ldB = [&](int buf, int h) {
    const unsigned b = buf * 65536 + 32768 + h * 16384;
    #pragma unroll
    for (int n = 0; n < 2; ++n) {
      const unsigned s = (unsigned)(wc * 32 + n * 16 + rA);
      #pragma unroll
      for (int kk = 0; kk < 2; ++kk) {
        const unsigned kb = kk * 64 + kg * 16;
        bq[h * 2 + n][kk] = *reinterpret_cast<const bf16x8*>(&lds[b + s * 128 + (kb ^ key)]);
      }
    }
  };
  auto mfma_half = [&](int hm, int hn) {   // one C-quadrant x K=64: 16 MFMA
    #pragma unroll
    for (int m = 0; m < 4; ++m)
      #pragma unroll
      for (int n = 0; n < 2; ++n)
        #pragma unroll
        for (int kk = 0; kk < 2; ++kk) {
          const int mi = hm * 4 + m, ni = hn * 2 + n;
          acc[mi][ni] = __builtin_amdgcn_mfma_f32_16x16x32_bf16(
              af[m][kk], bq[ni][kk], acc[mi][ni], 0, 0, 0);
        }
  };

  // per-otile epilogue (register-light). C/D: col=lane&15, row=(lane>>4)*4+reg
  auto epilogue = [&](int ot) {
    const int v_out = (nx0 + ot) * 4 + wc;
    const float4* cp = reinterpret_cast<const float4*>(clip + (size_t)v_out * Dn) + lane * 2;
    const float4 c0 = cp[0], c1 = cp[1];
    #pragma unroll
    for (int gq = 0; gq < 4; ++gq) {
      float sum = 0.f;
      #pragma unroll
      for (int m2 = 0; m2 < 2; ++m2) {
        const int mi = gq * 2 + m2;
        #pragma unroll
        for (int reg = 0; reg < 4; ++reg) {
          float rm = fmaxf(fmaxf(acc[mi][0][reg], acc[mi][1][reg]),
                           fmaxf(acc[mi][2][reg], acc[mi][3][reg]));
          rm = fmaxf(rm, __shfl_xor(rm, 1, 64));
          rm = fmaxf(rm, __shfl_xor(rm, 2, 64));
          rm = fmaxf(rm, __shfl_xor(rm, 4, 64));
          rm = fmaxf(rm, __shfl_xor(rm, 8, 64));   // max over all 64 f-cols
          sum += rm;
        }
      }
      sum += __shfl_xor(sum, 16, 64);
      sum += __shfl_xor(sum, 32, 64);              // sum over 32 q-rows
      const float4* tp = reinterpret_cast<const float4*>(
          text + (size_t)(by * 8 + wr * 4 + gq) * Dn) + lane * 2;
      const float4 t0 = tp[0], t1 = tp[1];
      float gd = t0.x*c0.x + t0.y*c0.y + t0.z*c0.z + t0.w*c0.w
               + t1.x*c1.x + t1.y*c1.y + t1.z*c1.z + t1.w*c1.w;
      gd += __shfl_xor(gd, 1, 64);  gd += __shfl_xor(gd, 2, 64);
      gd += __shfl_xor(gd, 4, 64);  gd += __shfl_xor(gd, 8, 64);
      gd += __shfl_xor(gd, 16, 64); gd += __shfl_xor(gd, 32, 64);
      if (lane == 0)
        out[(by * 8 + wr * 4 + gq) * Vn + v_out] = coefG * gd + coefL * sum;
    }
    #pragma unroll
    for (int i = 0; i < 8; ++i)
      #pragma unroll
      for (int j = 0; j < 4; ++j)
        acc[i][j] = {0.f, 0.f, 0.f, 0.f};
  };

  // prologue: tile0 fully + tile1 {A0,B0,B1} -> vmcnt(6) = tile0 landed
  stage(0, 0, 0, 0); stage(0, 1, 0, 0); stage(0, 1, 1, 0); stage(0, 0, 1, 0);
  stage(1, 0, 0, 1); stage(1, 1, 0, 1); stage(1, 1, 1, 1);
  VM6(); BAR();

  auto tile_step = [&](int g, int buf) {
    // reads for q00/q01: A0(8), B0(4) then B1(4) last (order pinned)
    ldA(buf, 0); ldB(buf, 0);
    SBAR();
    ldB(buf, 1);
    SBAR();
    if (g + 1 < GT) stage(buf ^ 1, 0, 1, g + 1);          // A1(g+1) -> other buf
    LGKM(4);                                               // A0,B0 landed
    __builtin_amdgcn_s_setprio(1);
    mfma_half(0, 0);                                       // B1 drains underneath
    __builtin_amdgcn_s_setprio(0);
    LGKM(0);                                               // B1 landed
    __builtin_amdgcn_s_setprio(1);
    mfma_half(0, 1);
    __builtin_amdgcn_s_setprio(0);
    BAR();                                                 // A0,B0,B1 slots free
    ldA(buf, 1);                                           // A1 -> af (reuse)
    SBAR();
    if (g + 2 < GT) {                                      // restage this buf
      stage(buf, 0, 0, g + 2);
      stage(buf, 1, 0, g + 2);
      stage(buf, 1, 1, g + 2);
    }
    LGKM(0);                                               // A1 landed
    __builtin_amdgcn_s_setprio(1);
    mfma_half(1, 1);
    mfma_half(1, 0);
    __builtin_amdgcn_s_setprio(0);
    if (g < GT - 2) { VM6(); } else { VM0(); }             // next tile landed
    if ((g & 7) == 7) epilogue(g >> 3);                    // otile done
    BAR();
  };

  for (int t = 0; t < GT; t += 2) {
    tile_step(t, 0);
    tile_step(t + 1, 1);
  }
}

extern "C" void kernel_launch(void* const* d_in, const int* in_sizes, int n_in,
                              void* d_out, int out_size, void* d_ws, size_t ws_size,
                              hipStream_t stream) {
  const float* text        = (const float*)d_in[0];
  const float* clip        = (const float*)d_in[1];
  const float* concept     = (const float*)d_in[2];
  const float* frames      = (const float*)d_in[3];
  const float* logit_scale = (const float*)d_in[4];
  float* out = (float*)d_out;

  uint16_t* Abf = (uint16_t*)d_ws;              //  8192*512 bf16 = 8 MiB
  uint16_t* Bbf = Abf + (size_t)Mn * Kn;        // 16384*512 bf16 = 16 MiB

  normalize_rows<<<Mn / 4, 256, 0, stream>>>(concept, (uint4*)Abf);
  normalize_rows<<<Nn / 4, 256, 0, stream>>>(frames, (uint4*)Bbf);
  maxsim256_kernel<<<256, 512, 0, stream>>>(Abf, Bbf, text, clip, logit_scale, out);
}